// Round 6
// baseline (178.528 us; speedup 1.0000x reference)
//
#include <hip/hip_runtime.h>
#include <math.h>

// B*S = 8192 tokens, K=8, N_BASIS=32, RANK=8, D_MODEL=256, D_HID=1024
// ws (bytes): wr f32 [0, 1.0M) | h f32 [1.0M, 3.0M) | wrAh/wrAl bf16 frags [3.0M, 4.0M)
//             | bf1h,bf1l,bf2h,bf2l [4.0M, 4.5M) | wfh,wfl [4.5M, 5.5M)   (~5.8 MB total)
// No g round-trip: down-proj fused into stageB.

typedef unsigned short u16;
typedef __attribute__((ext_vector_type(8))) __bf16 bf16x8;
typedef __attribute__((ext_vector_type(4))) float f32x4;
union ABCast { float4 f; bf16x8 v; };
union BFBits { __bf16 b; u16 u; };
union Pack8 { u16 u[8]; float4 f; };

__device__ __forceinline__ float gelu_exact(float v) {
    return 0.5f * v * (1.0f + erff(v * 0.70710678118654752440f));
}
__device__ __forceinline__ u16 f2bf_bits(float f) { BFBits c; c.b = (__bf16)f; return c.u; }
__device__ __forceinline__ float bfbits2f(u16 u) { BFBits c; c.u = u; return (float)c.b; }

// ---------------- K1: routing -> wr f32 + wr A-frags (bf16 h/l) ----------------
// A-frag (16x16x32): lane holds row = l&15 (token), k = 8*(l>>4)+e (n).
__global__ __launch_bounds__(64) void k_route(
    const int* __restrict__ nidx, const float* __restrict__ nw,
    const float* __restrict__ recipes, float* __restrict__ wr_out,
    u16* __restrict__ wrAh, u16* __restrict__ wrAl)
{
    const int t = blockIdx.x * 64 + threadIdx.x;
    float acc[32];
#pragma unroll
    for (int n = 0; n < 32; n++) acc[n] = 0.f;
#pragma unroll
    for (int k = 0; k < 8; k++) {
        const int   id = nidx[t * 8 + k];
        const float wk = nw[t * 8 + k];
        const float4* row = (const float4*)(recipes + id * 32);
        float v[32];
#pragma unroll
        for (int q = 0; q < 8; q++) {
            float4 f = row[q];
            v[q*4+0] = f.x; v[q*4+1] = f.y; v[q*4+2] = f.z; v[q*4+3] = f.w;
        }
        float m = v[0];
#pragma unroll
        for (int n = 1; n < 32; n++) m = fmaxf(m, v[n]);
        float s = 0.f;
#pragma unroll
        for (int n = 0; n < 32; n++) { float e = expf(v[n] - m); v[n] = e; s += e; }
        const float iv = wk / s;
#pragma unroll
        for (int n = 0; n < 32; n++) acc[n] += v[n] * iv;
    }
    float4* o = (float4*)(wr_out + t * 32);
#pragma unroll
    for (int q = 0; q < 8; q++)
        o[q] = make_float4(acc[q*4+0], acc[q*4+1], acc[q*4+2], acc[q*4+3]);

    // frag emission
    const int tg16 = t >> 4, tl = t & 15;
#pragma unroll
    for (int c = 0; c < 4; c++) {
        Pack8 ph, pl;
#pragma unroll
        for (int e = 0; e < 8; e++) {
            const float v = acc[c*8 + e];
            const u16 hb = f2bf_bits(v);
            ph.u[e] = hb;
            pl.u[e] = f2bf_bits(v - bfbits2f(hb));
        }
        const int lane = c * 16 + tl;
        *(float4*)(wrAh + (tg16*64 + lane)*8) = ph.f;
        *(float4*)(wrAl + (tg16*64 + lane)*8) = pl.f;
    }
}

// ---------------- K2: stage A  x[256] -> h[64], 8 tokens/block (unchanged) ----------------
__global__ __launch_bounds__(512) void k_stageA(
    const float* __restrict__ x, const float* __restrict__ wr,
    const float* __restrict__ A1, const float* __restrict__ A2,
    float* __restrict__ h_out)
{
    __shared__ float ca[8 * 1024];
    __shared__ float tl[8 * 1088];
    const int tid = threadIdx.x;
    const int t0  = blockIdx.x * 8;
    {
        const int e2 = tid * 2;
        float2 c[8];
#pragma unroll
        for (int tt = 0; tt < 8; tt++) c[tt] = make_float2(0.f, 0.f);
#pragma unroll 4
        for (int n = 0; n < 32; n++) {
            const float2 a = *(const float2*)(A1 + n * 1024 + e2);
#pragma unroll
            for (int tt = 0; tt < 8; tt++) {
                const float s = wr[(t0 + tt) * 32 + n];
                c[tt].x += s * a.x; c[tt].y += s * a.y;
            }
        }
#pragma unroll
        for (int tt = 0; tt < 8; tt++) *(float2*)(ca + tt * 1024 + e2) = c[tt];
    }
    __syncthreads();
    {
        const int t = tid >> 6, g = tid & 63, j = g >> 2, eh = g & 3;
        float xr[16];
#pragma unroll
        for (int i = 0; i < 16; i++) xr[i] = x[(t0 + t) * 256 + i * 16 + j];
        float tr[16];
#pragma unroll
        for (int q = 0; q < 16; q++) tr[q] = 0.f;
#pragma unroll
        for (int i = 0; i < 16; i++) {
            const float xv = xr[i];
#pragma unroll
            for (int q = 0; q < 4; q++) {
                const float4 cv = *(const float4*)(ca + t * 1024 + i * 64 + eh * 16 + q * 4);
                tr[q*4+0] += xv * cv.x; tr[q*4+1] += xv * cv.y;
                tr[q*4+2] += xv * cv.z; tr[q*4+3] += xv * cv.w;
            }
        }
#pragma unroll
        for (int q = 0; q < 4; q++)
            *(float4*)(tl + t * 1088 + j * 68 + eh * 16 + q * 4) =
                make_float4(tr[q*4+0], tr[q*4+1], tr[q*4+2], tr[q*4+3]);
    }
    __syncthreads();
    {
        const int e2 = tid * 2;
        float2 c[8];
#pragma unroll
        for (int tt = 0; tt < 8; tt++) c[tt] = make_float2(0.f, 0.f);
#pragma unroll 4
        for (int n = 0; n < 32; n++) {
            const float2 a = *(const float2*)(A2 + n * 1024 + e2);
#pragma unroll
            for (int tt = 0; tt < 8; tt++) {
                const float s = wr[(t0 + tt) * 32 + n];
                c[tt].x += s * a.x; c[tt].y += s * a.y;
            }
        }
#pragma unroll
        for (int tt = 0; tt < 8; tt++) *(float2*)(ca + tt * 1024 + e2) = c[tt];
    }
    __syncthreads();
    {
        const int t = tid >> 6, g = tid & 63, k = g >> 3, l = g & 7;
        float acc = 0.f;
#pragma unroll
        for (int j = 0; j < 16; j++) {
#pragma unroll
            for (int r = 0; r < 8; r++) {
                acc += tl[t * 1088 + j * 68 + r * 8 + k] *
                       ca[t * 1024 + r * 128 + j * 8 + l];
            }
        }
        h_out[(t0 + t) * 64 + g] = acc;
    }
}

// ---------------- K3a: basis banks -> bf16 h/l B-frags ----------------
// B-frag (16x16x32): lane: col = l&15, k-elem n = 8*(l>>4)+e.
// bank1 groups g = i*2+khalf (col c -> k = (g&1)*16+c); bank2 g = j*2+lhalf.
// layout: Bf[bank]_{h,l}[ ((r*16+g)*64 + l)*8 + e ]
__global__ __launch_bounds__(256) void k_bsplit(
    const float* __restrict__ B1, const float* __restrict__ B2,
    u16* __restrict__ o1h, u16* __restrict__ o1l,
    u16* __restrict__ o2h, u16* __restrict__ o2l)
{
    const int slot = blockIdx.x * 256 + threadIdx.x;   // 0..16383
    const int bank = slot >> 13, r = (slot >> 10) & 7, g = (slot >> 6) & 15, l = slot & 63;
    const int c = l & 15, nb = 8 * (l >> 4);
    const int base = (bank == 0)
        ? ((g >> 1) * 256 + r * 32 + (g & 1) * 16 + c)      // B1[n][i][r][k]
        : (r * 256 + (g >> 1) * 32 + (g & 1) * 16 + c);     // B2[n][r][j][l2]
    const float* S = (bank ? B2 : B1) + base + nb * 2048;
    Pack8 ph, pl;
#pragma unroll
    for (int e = 0; e < 8; e++) {
        const float v = S[e * 2048];
        const u16 hb = f2bf_bits(v);
        ph.u[e] = hb;
        pl.u[e] = f2bf_bits(v - bfbits2f(hb));
    }
    const int d = ((r * 16 + g) * 64 + l) * 8;
    *(float4*)((bank ? o2h : o1h) + d) = ph.f;
    *(float4*)((bank ? o2l : o1l) + d) = pl.f;
}

// ---------------- K3b: W[1024][256] -> bf16 h/l B-frags for down-proj ----------------
// Wf[ ((ng*32+kc)*64 + l)*8 + e ] = W[(kc*32 + 8*(l>>4)+e)*256 + ng*16 + (l&15)]
__global__ __launch_bounds__(256) void k_wsplit(
    const float* __restrict__ W, u16* __restrict__ wfh, u16* __restrict__ wfl)
{
    const int slot = blockIdx.x * 256 + threadIdx.x;   // 0..32767
    const int ng = slot >> 11, kc = (slot >> 6) & 31, l = slot & 63;
    const float* S = W + (kc * 32 + 8 * (l >> 4)) * 256 + ng * 16 + (l & 15);
    Pack8 ph, pl;
#pragma unroll
    for (int e = 0; e < 8; e++) {
        const float v = S[e * 256];
        const u16 hb = f2bf_bits(v);
        ph.u[e] = hb;
        pl.u[e] = f2bf_bits(v - bfbits2f(hb));
    }
    const int d = ((ng * 32 + kc) * 64 + l) * 8;
    *(float4*)(wfh + d) = ph.f;
    *(float4*)(wfl + d) = pl.f;
}

// ---------------- K4: fused stageB + down-proj, 16 tokens/block, 512 thr ----------------
// per r in 0..7: P1 core-build via MFMA (wave w<4: cb1 groups, w>=4: cb2 groups)
//               P2/P3: round-5 VALU layouts (measured 0 bank conflicts), 2 tokens/wave
// epilogue: gelu -> bf16 h/l split -> LDS A-frags (reuse) -> 192 MFMA down-proj -> y
__global__ __launch_bounds__(512, 4) void k_fusedB(
    const float* __restrict__ hin,
    const u16* __restrict__ wrAh, const u16* __restrict__ wrAl,
    const u16* __restrict__ bf1h, const u16* __restrict__ bf1l,
    const u16* __restrict__ bf2h, const u16* __restrict__ bf2l,
    const u16* __restrict__ wfh, const u16* __restrict__ wfl,
    const float* __restrict__ bias, float* __restrict__ y)
{
    __shared__ __align__(16) unsigned char smem[65536];
    float* hs  = (float*)smem;          // [16][64]        (phase 1)
    float* cb1 = hs + 1024;             // [16][264]
    float* cb2 = cb1 + 16 * 264;        // [16][264]
    float* t2  = cb2 + 16 * 264;        // [16][264]  end 54784 B
    u16* gAh = (u16*)smem;              // [32][64][8]     (phase 2, reuse)
    u16* gAl = gAh + 16384;             // end 65536 B

    const int tid = threadIdx.x;
    const int l   = tid & 63;
    const int w   = tid >> 6;           // 0..7
    const int tg  = blockIdx.x;         // 16-token group
    const int t0  = tg * 16;

    // stage h
    {
        const float2 hv = *(const float2*)(hin + t0 * 64 + tid * 2);
        hs[tid * 2] = hv.x; hs[tid * 2 + 1] = hv.y;
    }

    // wr A-frags (same for all waves)
    ABCast cu;
    cu.f = *(const float4*)(wrAh + (tg * 64 + l) * 8); const bf16x8 wra_h = cu.v;
    cu.f = *(const float4*)(wrAl + (tg * 64 + l) * 8); const bf16x8 wra_l = cu.v;

    // P1 assignment
    const bool isB2 = (w >= 4);
    const u16* bsrc_h = isB2 ? bf2h : bf1h;
    const u16* bsrc_l = isB2 ? bf2l : bf1l;
    float* cdst = isB2 ? cb2 : cb1;
    const int g0 = (w & 3) * 4;

    // P2/P3 maps (round-5)
    const int j2 = l >> 3, k42 = l & 7;
    const int k0 = (l & 7) * 4, l0 = (l >> 3) * 4;

    float o[2][4][4];
#pragma unroll
    for (int tt2 = 0; tt2 < 2; tt2++)
#pragma unroll
        for (int a = 0; a < 4; a++)
#pragma unroll
            for (int li = 0; li < 4; li++) o[tt2][a][li] = 0.f;

    float4 pbh[4], pbl[4];
#define LOADB(R) {                                                              \
    const int rb_ = (R);                                                        \
    _Pragma("unroll")                                                           \
    for (int gi = 0; gi < 4; gi++) {                                            \
        const int gg_ = g0 + gi;                                                \
        pbh[gi] = *(const float4*)(bsrc_h + ((rb_*16 + gg_)*64 + l)*8);         \
        pbl[gi] = *(const float4*)(bsrc_l + ((rb_*16 + gg_)*64 + l)*8);         \
    } }

    LOADB(0);

#pragma unroll 1
    for (int r = 0; r < 8; r++) {
        // ---- P1: MFMA core build ----
#pragma unroll
        for (int gi = 0; gi < 4; gi++) {
            cu.f = pbh[gi]; const bf16x8 bh = cu.v;
            cu.f = pbl[gi]; const bf16x8 bl = cu.v;
            f32x4 cc = {0.f, 0.f, 0.f, 0.f};
            cc = __builtin_amdgcn_mfma_f32_16x16x32_bf16(wra_h, bh, cc, 0, 0, 0);
            cc = __builtin_amdgcn_mfma_f32_16x16x32_bf16(wra_h, bl, cc, 0, 0, 0);
            cc = __builtin_amdgcn_mfma_f32_16x16x32_bf16(wra_l, bh, cc, 0, 0, 0);
            const int gg = g0 + gi;
            float* cd = cdst + (gg >> 1) * 32 + (gg & 1) * 16 + (l & 15);
#pragma unroll
            for (int reg = 0; reg < 4; reg++)
                cd[(4 * (l >> 4) + reg) * 264] = cc[reg];
        }
        if (r < 7) LOADB(r + 1);       // lands during P2/P3
        __syncthreads();

        // ---- P2: t2[t][j*32+k] = sum_i hs[t][i*8+j] * cb1[t][i*32+k] ----
#pragma unroll
        for (int tt2 = 0; tt2 < 2; tt2++) {
            const int t = w + tt2 * 8;
            float4 acc = make_float4(0.f, 0.f, 0.f, 0.f);
#pragma unroll
            for (int i = 0; i < 8; i++) {
                const float  hv = hs[t * 64 + i * 8 + j2];
                const float4 cv = *(const float4*)(cb1 + t * 264 + i * 32 + k42 * 4);
                acc.x += hv * cv.x; acc.y += hv * cv.y;
                acc.z += hv * cv.z; acc.w += hv * cv.w;
            }
            *(float4*)(t2 + t * 264 + j2 * 32 + k42 * 4) = acc;
        }
        __syncthreads();

        // ---- P3: o[a][li] += sum_j t2[t][j*32+k0+a] * cb2[t][j*32+l0+li] ----
#pragma unroll
        for (int tt2 = 0; tt2 < 2; tt2++) {
            const int t = w + tt2 * 8;
#pragma unroll
            for (int j = 0; j < 8; j++) {
                const float4 tv4 = *(const float4*)(t2  + t * 264 + j * 32 + k0);
                const float4 cv4 = *(const float4*)(cb2 + t * 264 + j * 32 + l0);
                const float tv[4] = {tv4.x, tv4.y, tv4.z, tv4.w};
                const float cv[4] = {cv4.x, cv4.y, cv4.z, cv4.w};
#pragma unroll
                for (int a = 0; a < 4; a++)
#pragma unroll
                    for (int li = 0; li < 4; li++)
                        o[tt2][a][li] += tv[a] * cv[li];
            }
        }
        __syncthreads();   // before next r overwrites cb1/cb2/t2
    }
#undef LOADB

    // ---- epilogue: gelu + split -> gA frags (LDS reuse; all P3 done at last barrier) ----
#pragma unroll
    for (int tt2 = 0; tt2 < 2; tt2++) {
        const int t = w + tt2 * 8;
        const int lane2 = (l0 >> 3) * 16 + t;
        const int e0 = l0 & 7;
#pragma unroll
        for (int a = 0; a < 4; a++) {
            u16 hv[4], lv[4];
#pragma unroll
            for (int li = 0; li < 4; li++) {
                const float v = gelu_exact(o[tt2][a][li]);
                const u16 hb = f2bf_bits(v);
                hv[li] = hb;
                lv[li] = f2bf_bits(v - bfbits2f(hb));
            }
            const int step = k0 + a;
            *(ushort4*)(gAh + (step * 64 + lane2) * 8 + e0) = make_ushort4(hv[0], hv[1], hv[2], hv[3]);
            *(ushort4*)(gAl + (step * 64 + lane2) * 8 + e0) = make_ushort4(lv[0], lv[1], lv[2], lv[3]);
        }
    }
    __syncthreads();

    // ---- down-proj: y[16][256] = g @ W + b ; wave w owns n-groups {2w, 2w+1} ----
    f32x4 dacc0 = {0.f, 0.f, 0.f, 0.f}, dacc1 = dacc0;
    const int wb0 = (w * 2 + 0) * 16384 + l * 8;   // (ng*32+kc)*512 + l*8
    const int wb1 = (w * 2 + 1) * 16384 + l * 8;
    float4 fh0 = *(const float4*)(wfh + wb0), fl0 = *(const float4*)(wfl + wb0);
    float4 fh1 = *(const float4*)(wfh + wb1), fl1 = *(const float4*)(wfl + wb1);
#pragma unroll 1
    for (int kc = 0; kc < 32; kc++) {
        cu.f = *(const float4*)(gAh + (kc * 64 + l) * 8); const bf16x8 ah = cu.v;
        cu.f = *(const float4*)(gAl + (kc * 64 + l) * 8); const bf16x8 al = cu.v;
        cu.f = fh0; const bf16x8 bh0 = cu.v;
        cu.f = fl0; const bf16x8 bl0 = cu.v;
        cu.f = fh1; const bf16x8 bh1 = cu.v;
        cu.f = fl1; const bf16x8 bl1 = cu.v;
        if (kc < 31) {
            fh0 = *(const float4*)(wfh + wb0 + (kc + 1) * 512);
            fl0 = *(const float4*)(wfl + wb0 + (kc + 1) * 512);
            fh1 = *(const float4*)(wfh + wb1 + (kc + 1) * 512);
            fl1 = *(const float4*)(wfl + wb1 + (kc + 1) * 512);
        }
        dacc0 = __builtin_amdgcn_mfma_f32_16x16x32_bf16(ah, bh0, dacc0, 0, 0, 0);
        dacc0 = __builtin_amdgcn_mfma_f32_16x16x32_bf16(ah, bl0, dacc0, 0, 0, 0);
        dacc0 = __builtin_amdgcn_mfma_f32_16x16x32_bf16(al, bh0, dacc0, 0, 0, 0);
        dacc1 = __builtin_amdgcn_mfma_f32_16x16x32_bf16(ah, bh1, dacc1, 0, 0, 0);
        dacc1 = __builtin_amdgcn_mfma_f32_16x16x32_bf16(ah, bl1, dacc1, 0, 0, 0);
        dacc1 = __builtin_amdgcn_mfma_f32_16x16x32_bf16(al, bh1, dacc1, 0, 0, 0);
    }
    // C-frag: col = l&15 (n within group), rows = tokens 4*(l>>4)+reg
    {
        const int n0 = (w * 2 + 0) * 16 + (l & 15);
        const int n1 = (w * 2 + 1) * 16 + (l & 15);
        const float b0 = bias[n0], b1 = bias[n1];
        const int tb = t0 + 4 * (l >> 4);
#pragma unroll
        for (int reg = 0; reg < 4; reg++) {
            y[(tb + reg) * 256 + n0] = dacc0[reg] + b0;
            y[(tb + reg) * 256 + n1] = dacc1[reg] + b1;
        }
    }
}

extern "C" void kernel_launch(void* const* d_in, const int* in_sizes, int n_in,
                              void* d_out, int out_size, void* d_ws, size_t ws_size,
                              hipStream_t stream)
{
    const float* x    = (const float*)d_in[0];
    const int*   nidx = (const int*)  d_in[1];
    const float* nw   = (const float*)d_in[2];
    const float* rec  = (const float*)d_in[3];
    const float* A1   = (const float*)d_in[4];
    const float* A2   = (const float*)d_in[5];
    const float* B1   = (const float*)d_in[6];
    const float* B2   = (const float*)d_in[7];
    const float* Wd   = (const float*)d_in[8];
    const float* bd   = (const float*)d_in[9];
    float* y  = (float*)d_out;

    float* wr  = (float*)d_ws;                   // 8192*32 f32
    float* h   = wr + 8192 * 32;                 // 8192*64 f32
    u16* wrAh  = (u16*)(h + 8192 * 64);          // 262144 u16
    u16* wrAl  = wrAh + 262144;
    u16* b1h   = wrAl + 262144;                  // 65536 u16 each
    u16* b1l   = b1h + 65536;
    u16* b2h   = b1l + 65536;
    u16* b2l   = b2h + 65536;
    u16* wfh   = b2l + 65536;                    // 262144 u16 each
    u16* wfl   = wfh + 262144;

    k_route <<<128,  64,  0, stream>>>(nidx, nw, rec, wr, wrAh, wrAl);
    k_stageA<<<1024, 512, 0, stream>>>(x, wr, A1, A2, h);
    k_bsplit<<<64,   256, 0, stream>>>(B1, B2, b1h, b1l, b2h, b2l);
    k_wsplit<<<128,  256, 0, stream>>>(Wd, wfh, wfl);
    k_fusedB<<<512,  512, 0, stream>>>(h, wrAh, wrAl, b1h, b1l, b2h, b2l, wfh, wfl, bd, y);
}

// Round 7
// 100.117 us; speedup vs baseline: 1.7832x; 1.7832x over previous
//
#include <hip/hip_runtime.h>
#include <math.h>

// B*S = 8192 tokens, K=8, N_BASIS=32, RANK=8, D_MODEL=256, D_HID=1024
// ws (bytes): wr f32 [0, 1.0M) | h f32 [1.0M, 3.0M) | wrAh/wrAl bf16 frags [3.0M, 4.0M)
//             | bf1h,bf1l,bf2h,bf2l [4.0M, 4.5M) | wfh,wfl [4.5M, 5.5M)   (~5.8 MB total)
// No g round-trip: down-proj fused into stageB.

typedef unsigned short u16;
typedef __attribute__((ext_vector_type(8))) __bf16 bf16x8;
typedef __attribute__((ext_vector_type(4))) float f32x4;
union ABCast { float4 f; bf16x8 v; };
union BFBits { __bf16 b; u16 u; };
union Pack8 { u16 u[8]; float4 f; };

__device__ __forceinline__ float gelu_exact(float v) {
    return 0.5f * v * (1.0f + erff(v * 0.70710678118654752440f));
}
__device__ __forceinline__ u16 f2bf_bits(float f) { BFBits c; c.b = (__bf16)f; return c.u; }
__device__ __forceinline__ float bfbits2f(u16 u) { BFBits c; c.u = u; return (float)c.b; }

// ---------------- K1: routing -> wr f32 + wr A-frags (bf16 h/l) ----------------
// A-frag (16x16x32): lane holds row = l&15 (token), k = 8*(l>>4)+e (n).
__global__ __launch_bounds__(64) void k_route(
    const int* __restrict__ nidx, const float* __restrict__ nw,
    const float* __restrict__ recipes, float* __restrict__ wr_out,
    u16* __restrict__ wrAh, u16* __restrict__ wrAl)
{
    const int t = blockIdx.x * 64 + threadIdx.x;
    float acc[32];
#pragma unroll
    for (int n = 0; n < 32; n++) acc[n] = 0.f;
#pragma unroll
    for (int k = 0; k < 8; k++) {
        const int   id = nidx[t * 8 + k];
        const float wk = nw[t * 8 + k];
        const float4* row = (const float4*)(recipes + id * 32);
        float v[32];
#pragma unroll
        for (int q = 0; q < 8; q++) {
            float4 f = row[q];
            v[q*4+0] = f.x; v[q*4+1] = f.y; v[q*4+2] = f.z; v[q*4+3] = f.w;
        }
        float m = v[0];
#pragma unroll
        for (int n = 1; n < 32; n++) m = fmaxf(m, v[n]);
        float s = 0.f;
#pragma unroll
        for (int n = 0; n < 32; n++) { float e = expf(v[n] - m); v[n] = e; s += e; }
        const float iv = wk / s;
#pragma unroll
        for (int n = 0; n < 32; n++) acc[n] += v[n] * iv;
    }
    float4* o = (float4*)(wr_out + t * 32);
#pragma unroll
    for (int q = 0; q < 8; q++)
        o[q] = make_float4(acc[q*4+0], acc[q*4+1], acc[q*4+2], acc[q*4+3]);

    // frag emission
    const int tg16 = t >> 4, tl = t & 15;
#pragma unroll
    for (int c = 0; c < 4; c++) {
        Pack8 ph, pl;
#pragma unroll
        for (int e = 0; e < 8; e++) {
            const float v = acc[c*8 + e];
            const u16 hb = f2bf_bits(v);
            ph.u[e] = hb;
            pl.u[e] = f2bf_bits(v - bfbits2f(hb));
        }
        const int lane = c * 16 + tl;
        *(float4*)(wrAh + (tg16*64 + lane)*8) = ph.f;
        *(float4*)(wrAl + (tg16*64 + lane)*8) = pl.f;
    }
}

// ---------------- K2: stage A  x[256] -> h[64], 8 tokens/block (unchanged) ----------------
__global__ __launch_bounds__(512) void k_stageA(
    const float* __restrict__ x, const float* __restrict__ wr,
    const float* __restrict__ A1, const float* __restrict__ A2,
    float* __restrict__ h_out)
{
    __shared__ float ca[8 * 1024];
    __shared__ float tl[8 * 1088];
    const int tid = threadIdx.x;
    const int t0  = blockIdx.x * 8;
    {
        const int e2 = tid * 2;
        float2 c[8];
#pragma unroll
        for (int tt = 0; tt < 8; tt++) c[tt] = make_float2(0.f, 0.f);
#pragma unroll 4
        for (int n = 0; n < 32; n++) {
            const float2 a = *(const float2*)(A1 + n * 1024 + e2);
#pragma unroll
            for (int tt = 0; tt < 8; tt++) {
                const float s = wr[(t0 + tt) * 32 + n];
                c[tt].x += s * a.x; c[tt].y += s * a.y;
            }
        }
#pragma unroll
        for (int tt = 0; tt < 8; tt++) *(float2*)(ca + tt * 1024 + e2) = c[tt];
    }
    __syncthreads();
    {
        const int t = tid >> 6, g = tid & 63, j = g >> 2, eh = g & 3;
        float xr[16];
#pragma unroll
        for (int i = 0; i < 16; i++) xr[i] = x[(t0 + t) * 256 + i * 16 + j];
        float tr[16];
#pragma unroll
        for (int q = 0; q < 16; q++) tr[q] = 0.f;
#pragma unroll
        for (int i = 0; i < 16; i++) {
            const float xv = xr[i];
#pragma unroll
            for (int q = 0; q < 4; q++) {
                const float4 cv = *(const float4*)(ca + t * 1024 + i * 64 + eh * 16 + q * 4);
                tr[q*4+0] += xv * cv.x; tr[q*4+1] += xv * cv.y;
                tr[q*4+2] += xv * cv.z; tr[q*4+3] += xv * cv.w;
            }
        }
#pragma unroll
        for (int q = 0; q < 4; q++)
            *(float4*)(tl + t * 1088 + j * 68 + eh * 16 + q * 4) =
                make_float4(tr[q*4+0], tr[q*4+1], tr[q*4+2], tr[q*4+3]);
    }
    __syncthreads();
    {
        const int e2 = tid * 2;
        float2 c[8];
#pragma unroll
        for (int tt = 0; tt < 8; tt++) c[tt] = make_float2(0.f, 0.f);
#pragma unroll 4
        for (int n = 0; n < 32; n++) {
            const float2 a = *(const float2*)(A2 + n * 1024 + e2);
#pragma unroll
            for (int tt = 0; tt < 8; tt++) {
                const float s = wr[(t0 + tt) * 32 + n];
                c[tt].x += s * a.x; c[tt].y += s * a.y;
            }
        }
#pragma unroll
        for (int tt = 0; tt < 8; tt++) *(float2*)(ca + tt * 1024 + e2) = c[tt];
    }
    __syncthreads();
    {
        const int t = tid >> 6, g = tid & 63, k = g >> 3, l = g & 7;
        float acc = 0.f;
#pragma unroll
        for (int j = 0; j < 16; j++) {
#pragma unroll
            for (int r = 0; r < 8; r++) {
                acc += tl[t * 1088 + j * 68 + r * 8 + k] *
                       ca[t * 1024 + r * 128 + j * 8 + l];
            }
        }
        h_out[(t0 + t) * 64 + g] = acc;
    }
}

// ---------------- K3a: basis banks -> bf16 h/l B-frags ----------------
// B-frag (16x16x32): lane: col = l&15, k-elem n = 8*(l>>4)+e.
// bank1 groups g = i*2+khalf (col c -> k = (g&1)*16+c); bank2 g = j*2+lhalf.
// layout: Bf[bank]_{h,l}[ ((r*16+g)*64 + l)*8 + e ]
__global__ __launch_bounds__(256) void k_bsplit(
    const float* __restrict__ B1, const float* __restrict__ B2,
    u16* __restrict__ o1h, u16* __restrict__ o1l,
    u16* __restrict__ o2h, u16* __restrict__ o2l)
{
    const int slot = blockIdx.x * 256 + threadIdx.x;   // 0..16383
    const int bank = slot >> 13, r = (slot >> 10) & 7, g = (slot >> 6) & 15, l = slot & 63;
    const int c = l & 15, nb = 8 * (l >> 4);
    const int base = (bank == 0)
        ? ((g >> 1) * 256 + r * 32 + (g & 1) * 16 + c)      // B1[n][i][r][k]
        : (r * 256 + (g >> 1) * 32 + (g & 1) * 16 + c);     // B2[n][r][j][l2]
    const float* S = (bank ? B2 : B1) + base + nb * 2048;
    Pack8 ph, pl;
#pragma unroll
    for (int e = 0; e < 8; e++) {
        const float v = S[e * 2048];
        const u16 hb = f2bf_bits(v);
        ph.u[e] = hb;
        pl.u[e] = f2bf_bits(v - bfbits2f(hb));
    }
    const int d = ((r * 16 + g) * 64 + l) * 8;
    *(float4*)((bank ? o2h : o1h) + d) = ph.f;
    *(float4*)((bank ? o2l : o1l) + d) = pl.f;
}

// ---------------- K3b: W[1024][256] -> bf16 h/l B-frags for down-proj ----------------
// Wf[ ((ng*32+kc)*64 + l)*8 + e ] = W[(kc*32 + 8*(l>>4)+e)*256 + ng*16 + (l&15)]
__global__ __launch_bounds__(256) void k_wsplit(
    const float* __restrict__ W, u16* __restrict__ wfh, u16* __restrict__ wfl)
{
    const int slot = blockIdx.x * 256 + threadIdx.x;   // 0..32767
    const int ng = slot >> 11, kc = (slot >> 6) & 31, l = slot & 63;
    const float* S = W + (kc * 32 + 8 * (l >> 4)) * 256 + ng * 16 + (l & 15);
    Pack8 ph, pl;
#pragma unroll
    for (int e = 0; e < 8; e++) {
        const float v = S[e * 256];
        const u16 hb = f2bf_bits(v);
        ph.u[e] = hb;
        pl.u[e] = f2bf_bits(v - bfbits2f(hb));
    }
    const int d = ((ng * 32 + kc) * 64 + l) * 8;
    *(float4*)(wfh + d) = ph.f;
    *(float4*)(wfl + d) = pl.f;
}

// ---------------- K4: fused stageB + down-proj, 16 tokens/block, 512 thr ----------------
// per r in 0..7: P1 core-build via MFMA (wave w<4: cb1 groups, w>=4: cb2 groups)
//               P2/P3: round-5 VALU layouts (measured 0 bank conflicts), 2 tokens/wave
// epilogue: gelu -> bf16 h/l split -> LDS A-frags (reuse) -> 192 MFMA down-proj -> y
// NOTE: launch_bounds min-waves kept at 2 (VGPR cap 256). (512,4) forced 64 VGPR -> 450MB
// of scratch spill traffic (round 6: FETCH 153MB/WRITE 316MB). Basis-frag loads are per-r
// (not cross-phase prefetched) to keep peak live state ~100 VGPR.
__global__ __launch_bounds__(512, 2) void k_fusedB(
    const float* __restrict__ hin,
    const u16* __restrict__ wrAh, const u16* __restrict__ wrAl,
    const u16* __restrict__ bf1h, const u16* __restrict__ bf1l,
    const u16* __restrict__ bf2h, const u16* __restrict__ bf2l,
    const u16* __restrict__ wfh, const u16* __restrict__ wfl,
    const float* __restrict__ bias, float* __restrict__ y)
{
    __shared__ __align__(16) unsigned char smem[65536];
    float* hs  = (float*)smem;          // [16][64]        (phase 1)
    float* cb1 = hs + 1024;             // [16][264]
    float* cb2 = cb1 + 16 * 264;        // [16][264]
    float* t2  = cb2 + 16 * 264;        // [16][264]  end 54784 B
    u16* gAh = (u16*)smem;              // [32][64][8]     (phase 2, reuse)
    u16* gAl = gAh + 16384;             // end 65536 B

    const int tid = threadIdx.x;
    const int l   = tid & 63;
    const int w   = tid >> 6;           // 0..7
    const int tg  = blockIdx.x;         // 16-token group
    const int t0  = tg * 16;

    // stage h
    {
        const float2 hv = *(const float2*)(hin + t0 * 64 + tid * 2);
        hs[tid * 2] = hv.x; hs[tid * 2 + 1] = hv.y;
    }

    // wr A-frags (same for all waves)
    ABCast cu;
    cu.f = *(const float4*)(wrAh + (tg * 64 + l) * 8); const bf16x8 wra_h = cu.v;
    cu.f = *(const float4*)(wrAl + (tg * 64 + l) * 8); const bf16x8 wra_l = cu.v;

    // P1 assignment
    const bool isB2 = (w >= 4);
    const u16* bsrc_h = isB2 ? bf2h : bf1h;
    const u16* bsrc_l = isB2 ? bf2l : bf1l;
    float* cdst = isB2 ? cb2 : cb1;
    const int g0 = (w & 3) * 4;

    // P2/P3 maps (round-5)
    const int j2 = l >> 3, k42 = l & 7;
    const int k0 = (l & 7) * 4, l0 = (l >> 3) * 4;

    float o[2][4][4];
#pragma unroll
    for (int tt2 = 0; tt2 < 2; tt2++)
#pragma unroll
        for (int a = 0; a < 4; a++)
#pragma unroll
            for (int li = 0; li < 4; li++) o[tt2][a][li] = 0.f;

#pragma unroll 1
    for (int r = 0; r < 8; r++) {
        // ---- P1: MFMA core build (loads issued here, not carried across phases) ----
#pragma unroll
        for (int gi = 0; gi < 4; gi++) {
            const int gg = g0 + gi;
            cu.f = *(const float4*)(bsrc_h + ((r*16 + gg)*64 + l)*8); const bf16x8 bh = cu.v;
            ABCast cu2;
            cu2.f = *(const float4*)(bsrc_l + ((r*16 + gg)*64 + l)*8); const bf16x8 bl = cu2.v;
            f32x4 cc = {0.f, 0.f, 0.f, 0.f};
            cc = __builtin_amdgcn_mfma_f32_16x16x32_bf16(wra_h, bh, cc, 0, 0, 0);
            cc = __builtin_amdgcn_mfma_f32_16x16x32_bf16(wra_h, bl, cc, 0, 0, 0);
            cc = __builtin_amdgcn_mfma_f32_16x16x32_bf16(wra_l, bh, cc, 0, 0, 0);
            float* cd = cdst + (gg >> 1) * 32 + (gg & 1) * 16 + (l & 15);
#pragma unroll
            for (int reg = 0; reg < 4; reg++)
                cd[(4 * (l >> 4) + reg) * 264] = cc[reg];
        }
        __syncthreads();

        // ---- P2: t2[t][j*32+k] = sum_i hs[t][i*8+j] * cb1[t][i*32+k] ----
#pragma unroll
        for (int tt2 = 0; tt2 < 2; tt2++) {
            const int t = w + tt2 * 8;
            float4 acc = make_float4(0.f, 0.f, 0.f, 0.f);
#pragma unroll
            for (int i = 0; i < 8; i++) {
                const float  hv = hs[t * 64 + i * 8 + j2];
                const float4 cv = *(const float4*)(cb1 + t * 264 + i * 32 + k42 * 4);
                acc.x += hv * cv.x; acc.y += hv * cv.y;
                acc.z += hv * cv.z; acc.w += hv * cv.w;
            }
            *(float4*)(t2 + t * 264 + j2 * 32 + k42 * 4) = acc;
        }
        __syncthreads();

        // ---- P3: o[a][li] += sum_j t2[t][j*32+k0+a] * cb2[t][j*32+l0+li] ----
#pragma unroll
        for (int tt2 = 0; tt2 < 2; tt2++) {
            const int t = w + tt2 * 8;
#pragma unroll
            for (int j = 0; j < 8; j++) {
                const float4 tv4 = *(const float4*)(t2  + t * 264 + j * 32 + k0);
                const float4 cv4 = *(const float4*)(cb2 + t * 264 + j * 32 + l0);
                const float tv[4] = {tv4.x, tv4.y, tv4.z, tv4.w};
                const float cv[4] = {cv4.x, cv4.y, cv4.z, cv4.w};
#pragma unroll
                for (int a = 0; a < 4; a++)
#pragma unroll
                    for (int li = 0; li < 4; li++)
                        o[tt2][a][li] += tv[a] * cv[li];
            }
        }
        __syncthreads();   // before next r overwrites cb1/cb2/t2
    }

    // ---- epilogue: gelu + split -> gA frags (LDS reuse; all P3 done at last barrier) ----
#pragma unroll
    for (int tt2 = 0; tt2 < 2; tt2++) {
        const int t = w + tt2 * 8;
        const int lane2 = (l0 >> 3) * 16 + t;
        const int e0 = l0 & 7;
#pragma unroll
        for (int a = 0; a < 4; a++) {
            u16 hv[4], lv[4];
#pragma unroll
            for (int li = 0; li < 4; li++) {
                const float v = gelu_exact(o[tt2][a][li]);
                const u16 hb = f2bf_bits(v);
                hv[li] = hb;
                lv[li] = f2bf_bits(v - bfbits2f(hb));
            }
            const int step = k0 + a;
            *(ushort4*)(gAh + (step * 64 + lane2) * 8 + e0) = make_ushort4(hv[0], hv[1], hv[2], hv[3]);
            *(ushort4*)(gAl + (step * 64 + lane2) * 8 + e0) = make_ushort4(lv[0], lv[1], lv[2], lv[3]);
        }
    }
    __syncthreads();

    // ---- down-proj: y[16][256] = g @ W + b ; wave w owns n-groups {2w, 2w+1} ----
    f32x4 dacc0 = {0.f, 0.f, 0.f, 0.f}, dacc1 = dacc0;
    const int wb0 = (w * 2 + 0) * 16384 + l * 8;   // (ng*32+kc)*512 + l*8
    const int wb1 = (w * 2 + 1) * 16384 + l * 8;
#pragma unroll 1
    for (int kc = 0; kc < 32; kc++) {
        cu.f = *(const float4*)(gAh + (kc * 64 + l) * 8); const bf16x8 ah = cu.v;
        cu.f = *(const float4*)(gAl + (kc * 64 + l) * 8); const bf16x8 al = cu.v;
        ABCast c0, c1, c2, c3;
        c0.f = *(const float4*)(wfh + wb0 + kc * 512); const bf16x8 bh0 = c0.v;
        c1.f = *(const float4*)(wfl + wb0 + kc * 512); const bf16x8 bl0 = c1.v;
        c2.f = *(const float4*)(wfh + wb1 + kc * 512); const bf16x8 bh1 = c2.v;
        c3.f = *(const float4*)(wfl + wb1 + kc * 512); const bf16x8 bl1 = c3.v;
        dacc0 = __builtin_amdgcn_mfma_f32_16x16x32_bf16(ah, bh0, dacc0, 0, 0, 0);
        dacc0 = __builtin_amdgcn_mfma_f32_16x16x32_bf16(ah, bl0, dacc0, 0, 0, 0);
        dacc0 = __builtin_amdgcn_mfma_f32_16x16x32_bf16(al, bh0, dacc0, 0, 0, 0);
        dacc1 = __builtin_amdgcn_mfma_f32_16x16x32_bf16(ah, bh1, dacc1, 0, 0, 0);
        dacc1 = __builtin_amdgcn_mfma_f32_16x16x32_bf16(ah, bl1, dacc1, 0, 0, 0);
        dacc1 = __builtin_amdgcn_mfma_f32_16x16x32_bf16(al, bh1, dacc1, 0, 0, 0);
    }
    // C-frag: col = l&15 (n within group), rows = tokens 4*(l>>4)+reg
    {
        const int n0 = (w * 2 + 0) * 16 + (l & 15);
        const int n1 = (w * 2 + 1) * 16 + (l & 15);
        const float b0 = bias[n0], b1 = bias[n1];
        const int tb = t0 + 4 * (l >> 4);
#pragma unroll
        for (int reg = 0; reg < 4; reg++) {
            y[(tb + reg) * 256 + n0] = dacc0[reg] + b0;
            y[(tb + reg) * 256 + n1] = dacc1[reg] + b1;
        }
    }
}

extern "C" void kernel_launch(void* const* d_in, const int* in_sizes, int n_in,
                              void* d_out, int out_size, void* d_ws, size_t ws_size,
                              hipStream_t stream)
{
    const float* x    = (const float*)d_in[0];
    const int*   nidx = (const int*)  d_in[1];
    const float* nw   = (const float*)d_in[2];
    const float* rec  = (const float*)d_in[3];
    const float* A1   = (const float*)d_in[4];
    const float* A2   = (const float*)d_in[5];
    const float* B1   = (const float*)d_in[6];
    const float* B2   = (const float*)d_in[7];
    const float* Wd   = (const float*)d_in[8];
    const float* bd   = (const float*)d_in[9];
    float* y  = (float*)d_out;

    float* wr  = (float*)d_ws;                   // 8192*32 f32
    float* h   = wr + 8192 * 32;                 // 8192*64 f32
    u16* wrAh  = (u16*)(h + 8192 * 64);          // 262144 u16
    u16* wrAl  = wrAh + 262144;
    u16* b1h   = wrAl + 262144;                  // 65536 u16 each
    u16* b1l   = b1h + 65536;
    u16* b2h   = b1l + 65536;
    u16* b2l   = b2h + 65536;
    u16* wfh   = b2l + 65536;                    // 262144 u16 each
    u16* wfl   = wfh + 262144;

    k_route <<<128,  64,  0, stream>>>(nidx, nw, rec, wr, wrAh, wrAl);
    k_stageA<<<1024, 512, 0, stream>>>(x, wr, A1, A2, h);
    k_bsplit<<<64,   256, 0, stream>>>(B1, B2, b1h, b1l, b2h, b2l);
    k_wsplit<<<128,  256, 0, stream>>>(Wd, wfh, wfl);
    k_fusedB<<<512,  512, 0, stream>>>(h, wrAh, wrAl, b1h, b1l, b2h, b2l, wfh, wfl, bd, y);
}